// Round 2
// 518.341 us; speedup vs baseline: 1.0533x; 1.0533x over previous
//
#include <hip/hip_runtime.h>
#include <hip/hip_bf16.h>
#include <stdint.h>

// Problem constants
#define E_NUM 8
#define D_DIM 512
#define H_DIM 2048
#define NTOK 16384   // B*S = 8*2048

typedef __bf16 bf16;
typedef __bf16 bf16x8 __attribute__((ext_vector_type(8)));
typedef float  f32x4  __attribute__((ext_vector_type(4)));

// GEMM tiling: 256x256 tile, BK=64, 8 waves (2M x 4N), 512 threads.
// 2-phase double-buffered global_load_lds staging (T3-lite). LDS = 128KB -> 1 block/CU.
// XCD-aware swizzle: all N-chunks of one row-block share lin%8 -> same XCD L2.
#define BM 256
#define BN 256
#define BK 64

// async global->LDS, 16B per lane
typedef __attribute__((address_space(1))) const void* gas_cp;
typedef __attribute__((address_space(3))) void* las_p;
__device__ __forceinline__ void gl_lds16(const void* g, void* l) {
  __builtin_amdgcn_global_load_lds((gas_cp)g, (las_p)l, 16, 0, 0);
}

// Workspace layout (bytes)
static const size_t OFF_FILL = 32;           // 8 ints (per-expert count after fill)
static const size_t OFF_LIST = 128;          // E*NTOK ints = 512KB
static const size_t OFF_XBF  = 1ull << 20;                              // bf16 [NTOK][D] = 16.8MB
static const size_t OFF_W1T  = OFF_XBF + (size_t)NTOK*D_DIM*2;          // bf16 [E][H][D]
static const size_t OFF_W2T  = OFF_W1T + (size_t)E_NUM*H_DIM*D_DIM*2;   // bf16 [E][D][H]
static const size_t OFF_HBUF = OFF_W2T + (size_t)E_NUM*H_DIM*D_DIM*2;   // bf16 [<=34816][H] (256-pad)

// rowbase for expert e, computed from counts (all blocks agree; cnt final at kernel launch)
__device__ __forceinline__ int rowbase_of(const int* cnt, int e) {
  int acc = 0;
  for (int i = 0; i < e; i++) acc += (cnt[i] + BM - 1) & ~(BM - 1);
  return acc;
}

// ---------------- routing: fill lists + counts in one kernel ----------------
__global__ void fill_kernel(const int* __restrict__ assign, int* __restrict__ fill,
                            int* __restrict__ lists) {
  int n = blockIdx.x * blockDim.x + threadIdx.x;
  if (n >= NTOK) return;
  int e0 = assign[2*n], e1 = assign[2*n+1];
  int p0 = atomicAdd(&fill[e0], 1);
  lists[e0 * NTOK + p0] = n;
  if (e1 != e0) {
    int p1 = atomicAdd(&fill[e1], 1);
    lists[e1 * NTOK + p1] = n;
  }
}

// ---------------- x f32 -> bf16 (un-gathered, one pass) ----------------
__global__ void cvt_x(const float* __restrict__ x, bf16* __restrict__ xbf) {
  size_t i = ((size_t)blockIdx.x * 256 + threadIdx.x) * 8;
  float4 a = *reinterpret_cast<const float4*>(x + i);
  float4 b = *reinterpret_cast<const float4*>(x + i + 4);
  bf16x8 o;
  o[0] = (bf16)a.x; o[1] = (bf16)a.y; o[2] = (bf16)a.z; o[3] = (bf16)a.w;
  o[4] = (bf16)b.x; o[5] = (bf16)b.y; o[6] = (bf16)b.z; o[7] = (bf16)b.w;
  *reinterpret_cast<bf16x8*>(xbf + i) = o;
}

// ---------------- weight transpose + cvt: [E][R][C] f32 -> [E][C][R] bf16 ----------------
__global__ void transpose_cvt(const float* __restrict__ in, bf16* __restrict__ out,
                              int R, int C) {
  __shared__ float tile[32][33];
  int e = blockIdx.z;
  int c0 = blockIdx.x * 32, r0 = blockIdx.y * 32;
  const float* src = in + (size_t)e * R * C;
  bf16* dst = out + (size_t)e * R * C;
  int tx = threadIdx.x, ty = threadIdx.y;  // 32 x 8
  #pragma unroll
  for (int i = 0; i < 32; i += 8)
    tile[ty + i][tx] = src[(size_t)(r0 + ty + i) * C + c0 + tx];
  __syncthreads();
  #pragma unroll
  for (int i = 0; i < 32; i += 8)
    dst[(size_t)(c0 + ty + i) * R + r0 + tx] = (bf16)tile[tx][ty + i];
}

// ---------------- GEMM1: h = relu(Xg @ W1 + b1), bf16 out to hbuf ----------------
// grid: 1D, lin = xcd + 8*(nc + NC1*rbHi); rb = rbHi*8 + xcd; NC1 = 8 chunks over H
#define NC1 (H_DIM / BN)   // 8
__global__ __launch_bounds__(512, 2) void gemm1(
    const bf16* __restrict__ xbf, const bf16* __restrict__ w1t,
    const float* __restrict__ b1, const int* __restrict__ lists,
    const int* __restrict__ cnt, bf16* __restrict__ hbuf) {
  int lin = blockIdx.x;
  int xcd = lin & 7;
  int rem = lin >> 3;
  int nc  = rem & (NC1 - 1);
  int rb  = (rem >> 3) * 8 + xcd;          // rem >> log2(NC1)
  int e   = rb >> 6;                        // rb / 64 (64 row-blocks of 256 per expert)
  int m0  = (rb & 63) * BM;
  int ce  = cnt[e];
  if (m0 >= ce) return;
  int n0 = nc * BN;
  int rbase = rowbase_of(cnt, e);

  __shared__ bf16 xs[2][BM * BK];   // [row][k], stride 64 elems, double-buffered (32KB ea)
  __shared__ bf16 bs[2][BN * BK];
  __shared__ int tok[BM];

  int tid = threadIdx.x;
  if (tid < BM) {
    int r = m0 + tid;
    tok[tid] = (r < ce) ? lists[e * NTOK + r] : lists[e * NTOK];
  }
  __syncthreads();

  const bf16* w1e = w1t + (size_t)e * H_DIM * D_DIM + (size_t)n0 * D_DIM;
  int wave = tid >> 6, lane = tid & 63;
  int quad = lane >> 4, l16 = lane & 15;
  int lr = lane >> 3, lc = (lane & 7) * 8;   // staging: 8 rows x 64 cols per wave-instr
  int wm = (wave >> 2) * 128, wn = (wave & 3) * 64;   // 2M x 4N wave grid
  f32x4 acc[8][4] = {};

  auto stage = [&](int buf, int k0) {
    #pragma unroll
    for (int i = 0; i < 4; i++) {
      int s = wave * 4 + i;                 // segment: rows [8s, 8s+8), s in [0,32)
      int t = tok[s * 8 + lr];
      gl_lds16(xbf + (size_t)t * D_DIM + k0 + lc, &xs[buf][s * 512]);
    }
    #pragma unroll
    for (int i = 0; i < 4; i++) {
      int s = wave * 4 + i;
      gl_lds16(w1e + (size_t)(s * 8 + lr) * D_DIM + k0 + lc, &bs[buf][s * 512]);
    }
  };

  const int nk = D_DIM / BK;  // 8
  stage(0, 0);
  for (int ki = 0; ki < nk; ki++) {
    __syncthreads();                                       // drains buf[ki&1] loads
    if (ki + 1 < nk) stage((ki + 1) & 1, (ki + 1) * BK);   // fly during compute
    const bf16* xsc = xs[ki & 1];
    const bf16* bsc = bs[ki & 1];
    #pragma unroll
    for (int kk = 0; kk < BK; kk += 32) {
      bf16x8 bfr[4];
      #pragma unroll
      for (int j = 0; j < 4; j++)
        bfr[j] = *reinterpret_cast<const bf16x8*>(&bsc[(wn + j * 16 + l16) * BK + kk + quad * 8]);
      #pragma unroll
      for (int i = 0; i < 8; i++) {
        bf16x8 af = *reinterpret_cast<const bf16x8*>(&xsc[(wm + i * 16 + l16) * BK + kk + quad * 8]);
        #pragma unroll
        for (int j = 0; j < 4; j++)
          acc[i][j] = __builtin_amdgcn_mfma_f32_16x16x32_bf16(af, bfr[j], acc[i][j], 0, 0, 0);
      }
    }
  }

  bf16* hrow = hbuf + (size_t)(rbase + m0) * H_DIM;
  #pragma unroll
  for (int i = 0; i < 8; i++) {
    int row = wm + i * 16 + quad * 4;
    #pragma unroll
    for (int j = 0; j < 4; j++) {
      int col = n0 + wn + j * 16 + l16;
      float bias = b1[e * H_DIM + col];
      #pragma unroll
      for (int r = 0; r < 4; r++) {
        float v = acc[i][j][r] + bias;
        v = v > 0.f ? v : 0.f;
        hrow[(size_t)(row + r) * H_DIM + col] = (bf16)v;
      }
    }
  }
}

// ---------------- GEMM2: out += 0.5*(h @ W2 + b2), scattered fp32 atomicAdd ----------------
// same 256^2 2-phase structure; NC2 = 2 chunks over D
#define NC2 (D_DIM / BN)   // 2
__global__ __launch_bounds__(512, 2) void gemm2(
    const bf16* __restrict__ hbuf, const bf16* __restrict__ w2t,
    const float* __restrict__ b2, const int* __restrict__ lists,
    const int* __restrict__ cnt, float* __restrict__ out) {
  int lin = blockIdx.x;
  int xcd = lin & 7;
  int rem = lin >> 3;
  int nc  = rem & (NC2 - 1);
  int rb  = (rem >> 1) * 8 + xcd;
  int e   = rb >> 6;
  int m0  = (rb & 63) * BM;
  int ce  = cnt[e];
  if (m0 >= ce) return;
  int n0 = nc * BN;
  int rbase = rowbase_of(cnt, e);

  __shared__ bf16 hs[2][BM * BK];
  __shared__ bf16 bs[2][BN * BK];
  __shared__ int tok[BM];

  int tid = threadIdx.x;
  if (tid < BM) {
    int r = m0 + tid;
    tok[tid] = (r < ce) ? lists[e * NTOK + r] : -1;
  }
  __syncthreads();

  const bf16* hbase = hbuf + (size_t)(rbase + m0) * H_DIM;
  const bf16* w2e = w2t + (size_t)e * H_DIM * D_DIM + (size_t)n0 * H_DIM;
  int wave = tid >> 6, lane = tid & 63;
  int quad = lane >> 4, l16 = lane & 15;
  int lr = lane >> 3, lc = (lane & 7) * 8;
  int wm = (wave >> 2) * 128, wn = (wave & 3) * 64;
  f32x4 acc[8][4] = {};

  auto stage = [&](int buf, int k0) {
    #pragma unroll
    for (int i = 0; i < 4; i++) {
      int s = wave * 4 + i;
      gl_lds16(hbase + (size_t)(s * 8 + lr) * H_DIM + k0 + lc, &hs[buf][s * 512]);
    }
    #pragma unroll
    for (int i = 0; i < 4; i++) {
      int s = wave * 4 + i;
      gl_lds16(w2e + (size_t)(s * 8 + lr) * H_DIM + k0 + lc, &bs[buf][s * 512]);
    }
  };

  const int nk = H_DIM / BK;  // 32
  stage(0, 0);
  for (int ki = 0; ki < nk; ki++) {
    __syncthreads();
    if (ki + 1 < nk) stage((ki + 1) & 1, (ki + 1) * BK);
    const bf16* hsc = hs[ki & 1];
    const bf16* bsc = bs[ki & 1];
    #pragma unroll
    for (int kk = 0; kk < BK; kk += 32) {
      bf16x8 bfr[4];
      #pragma unroll
      for (int j = 0; j < 4; j++)
        bfr[j] = *reinterpret_cast<const bf16x8*>(&bsc[(wn + j * 16 + l16) * BK + kk + quad * 8]);
      #pragma unroll
      for (int i = 0; i < 8; i++) {
        bf16x8 af = *reinterpret_cast<const bf16x8*>(&hsc[(wm + i * 16 + l16) * BK + kk + quad * 8]);
        #pragma unroll
        for (int j = 0; j < 4; j++)
          acc[i][j] = __builtin_amdgcn_mfma_f32_16x16x32_bf16(af, bfr[j], acc[i][j], 0, 0, 0);
      }
    }
  }

  #pragma unroll
  for (int i = 0; i < 8; i++) {
    int row = wm + i * 16 + quad * 4;
    #pragma unroll
    for (int j = 0; j < 4; j++) {
      int col = n0 + wn + j * 16 + l16;
      float bias = b2[e * D_DIM + col];
      #pragma unroll
      for (int r = 0; r < 4; r++) {
        int t = tok[row + r];
        if (t >= 0) {
          float v = 0.5f * (acc[i][j][r] + bias);
          atomicAdd(&out[(size_t)t * D_DIM + col], v);
        }
      }
    }
  }
}

// ---------------- launch ----------------
extern "C" void kernel_launch(void* const* d_in, const int* in_sizes, int n_in,
                              void* d_out, int out_size, void* d_ws, size_t ws_size,
                              hipStream_t stream) {
  const float* x      = (const float*)d_in[0];
  const int*   assign = (const int*)d_in[1];
  const float* W1     = (const float*)d_in[2];
  const float* b1     = (const float*)d_in[3];
  const float* W2     = (const float*)d_in[4];
  const float* b2     = (const float*)d_in[5];
  float* out = (float*)d_out;
  char* ws = (char*)d_ws;

  int* fill    = (int*)(ws + OFF_FILL);
  int* lists   = (int*)(ws + OFF_LIST);
  bf16* xbf    = (bf16*)(ws + OFF_XBF);
  bf16* w1t    = (bf16*)(ws + OFF_W1T);
  bf16* w2t    = (bf16*)(ws + OFF_W2T);
  bf16* hbuf   = (bf16*)(ws + OFF_HBUF);

  hipMemsetAsync(ws, 0, 128, stream);
  hipMemsetAsync(d_out, 0, (size_t)out_size * sizeof(float), stream);

  fill_kernel<<<NTOK / 256, 256, 0, stream>>>(assign, fill, lists);

  cvt_x<<<(NTOK * D_DIM) / (256 * 8), 256, 0, stream>>>(x, xbf);
  // W1 [E][D][H] -> W1T [E][H][D];  W2 [E][H][D] -> W2T [E][D][H]
  transpose_cvt<<<dim3(H_DIM / 32, D_DIM / 32, E_NUM), dim3(32, 8), 0, stream>>>(W1, w1t, D_DIM, H_DIM);
  transpose_cvt<<<dim3(D_DIM / 32, H_DIM / 32, E_NUM), dim3(32, 8), 0, stream>>>(W2, w2t, H_DIM, D_DIM);

  // 1D swizzled grids: total = (E*NTOK/BM) * NC, encode lin = xcd + 8*(nc + NC*rbHi)
  gemm1<<<(E_NUM * NTOK / BM) * NC1, 512, 0, stream>>>(xbf, w1t, b1, lists, fill, hbuf);
  gemm2<<<(E_NUM * NTOK / BM) * NC2, 512, 0, stream>>>(hbuf, w2t, b2, lists, fill, out);

  (void)in_sizes; (void)n_in; (void)ws_size;
}

// Round 6
// 399.175 us; speedup vs baseline: 1.3678x; 1.2985x over previous
//
#include <hip/hip_runtime.h>
#include <hip/hip_bf16.h>
#include <stdint.h>

// Problem constants
#define E_NUM 8
#define D_DIM 512
#define H_DIM 2048
#define NTOK 16384   // B*S = 8*2048

typedef __bf16 bf16;
typedef __bf16 bf16x8 __attribute__((ext_vector_type(8)));
typedef float  f32x4  __attribute__((ext_vector_type(4)));

// GEMM tiling: 256x256 tile, BK=64, 8 waves (2M x 4N), 512 threads.
// 2-phase double-buffered global_load_lds staging. LDS = 128KB -> 1 block/CU.
// T2 dual-side XOR swizzle: LDS row stride is 128B -> unswizzled ds_read_b128 is a
// 16-way bank conflict (measured 1.8e7 conflict cycles/dispatch). gl_lds requires a
// linear LDS dest, so we swizzle the per-lane GLOBAL source slot (slot^=lane>>3) and
// apply the same XOR on the read side (slot^=row&7). 2-way after fix (free, m136).
#define BM 256
#define BN 256
#define BK 64

// async global->LDS, 16B per lane
typedef __attribute__((address_space(1))) const void* gas_cp;
typedef __attribute__((address_space(3))) void* las_p;
__device__ __forceinline__ void gl_lds16(const void* g, void* l) {
  __builtin_amdgcn_global_load_lds((gas_cp)g, (las_p)l, 16, 0, 0);
}

// Workspace layout (bytes)
static const size_t OFF_FILL = 32;           // 8 ints (per-expert count after fill)
static const size_t OFF_LIST = 128;          // E*NTOK ints = 512KB
static const size_t OFF_XBF  = 1ull << 20;                              // bf16 [NTOK][D] = 16.8MB
static const size_t OFF_W1T  = OFF_XBF + (size_t)NTOK*D_DIM*2;          // bf16 [E][H][D]
static const size_t OFF_W2T  = OFF_W1T + (size_t)E_NUM*H_DIM*D_DIM*2;   // bf16 [E][D][H]
static const size_t OFF_HBUF = OFF_W2T + (size_t)E_NUM*H_DIM*D_DIM*2;   // bf16 [<=34816][H] (256-pad)

// rowbase for expert e, computed from counts (all blocks agree; cnt final at kernel launch)
__device__ __forceinline__ int rowbase_of(const int* cnt, int e) {
  int acc = 0;
  for (int i = 0; i < e; i++) acc += (cnt[i] + BM - 1) & ~(BM - 1);
  return acc;
}

// ---------------- routing: wave-aggregated fill (8 atomics/wave, not 128) ----------------
__global__ void fill_kernel(const int* __restrict__ assign, int* __restrict__ fill,
                            int* __restrict__ lists) {
  int n = blockIdx.x * blockDim.x + threadIdx.x;   // grid exact: no guard (ballot uniformity)
  int lane = threadIdx.x & 63;
  unsigned long long below = ((unsigned long long)1 << lane) - 1;
  int e0 = assign[2*n], e1 = assign[2*n+1];
  #pragma unroll
  for (int e = 0; e < E_NUM; e++) {
    bool h0 = (e0 == e);
    bool h1 = (e1 == e) && (e1 != e0);
    unsigned long long m0 = __ballot(h0);
    unsigned long long m1 = __ballot(h1);
    int c = __popcll(m0) + __popcll(m1);
    if (c > 0) {                                   // wave-uniform
      int leader = __ffsll((long long)(m0 | m1)) - 1;
      int b = 0;
      if (lane == leader) b = atomicAdd(&fill[e], c);
      b = __shfl(b, leader);
      if (h0) lists[e * NTOK + b + __popcll(m0 & below)] = n;
      if (h1) lists[e * NTOK + b + __popcll(m0) + __popcll(m1 & below)] = n;
    }
  }
}

// ---------------- x f32 -> bf16 (un-gathered, one pass) ----------------
__global__ void cvt_x(const float* __restrict__ x, bf16* __restrict__ xbf) {
  size_t i = ((size_t)blockIdx.x * 256 + threadIdx.x) * 8;
  float4 a = *reinterpret_cast<const float4*>(x + i);
  float4 b = *reinterpret_cast<const float4*>(x + i + 4);
  bf16x8 o;
  o[0] = (bf16)a.x; o[1] = (bf16)a.y; o[2] = (bf16)a.z; o[3] = (bf16)a.w;
  o[4] = (bf16)b.x; o[5] = (bf16)b.y; o[6] = (bf16)b.z; o[7] = (bf16)b.w;
  *reinterpret_cast<bf16x8*>(xbf + i) = o;
}

// ---------------- weight transpose + cvt: [E][R][C] f32 -> [E][C][R] bf16 ----------------
__global__ void transpose_cvt(const float* __restrict__ in, bf16* __restrict__ out,
                              int R, int C) {
  __shared__ float tile[32][33];
  int e = blockIdx.z;
  int c0 = blockIdx.x * 32, r0 = blockIdx.y * 32;
  const float* src = in + (size_t)e * R * C;
  bf16* dst = out + (size_t)e * R * C;
  int tx = threadIdx.x, ty = threadIdx.y;  // 32 x 8
  #pragma unroll
  for (int i = 0; i < 32; i += 8)
    tile[ty + i][tx] = src[(size_t)(r0 + ty + i) * C + c0 + tx];
  __syncthreads();
  #pragma unroll
  for (int i = 0; i < 32; i += 8)
    dst[(size_t)(c0 + ty + i) * R + r0 + tx] = (bf16)tile[tx][ty + i];
}

// ---------------- GEMM1: h = relu(Xg @ W1 + b1), bf16 out to hbuf ----------------
// grid: 1D, lin = xcd + 8*(nc + NC1*rbHi); rb = rbHi*8 + xcd; NC1 = 8 chunks over H
#define NC1 (H_DIM / BN)   // 8
__global__ __launch_bounds__(512, 2) void gemm1(
    const bf16* __restrict__ xbf, const bf16* __restrict__ w1t,
    const float* __restrict__ b1, const int* __restrict__ lists,
    const int* __restrict__ cnt, bf16* __restrict__ hbuf) {
  int lin = blockIdx.x;
  int xcd = lin & 7;
  int rem = lin >> 3;
  int nc  = rem & (NC1 - 1);
  int rb  = (rem >> 3) * 8 + xcd;          // rem >> log2(NC1)
  int e   = rb >> 6;                        // rb / 64 (64 row-blocks of 256 per expert)
  int m0  = (rb & 63) * BM;
  int ce  = cnt[e];
  if (m0 >= ce) return;
  int n0 = nc * BN;
  int rbase = rowbase_of(cnt, e);

  __shared__ bf16 xs[2][BM * BK];   // [row][k], stride 64 elems, double-buffered (32KB ea)
  __shared__ bf16 bs[2][BN * BK];
  __shared__ int tok[BM];

  int tid = threadIdx.x;
  if (tid < BM) {
    int r = m0 + tid;
    tok[tid] = (r < ce) ? lists[e * NTOK + r] : lists[e * NTOK];
  }
  __syncthreads();

  const bf16* w1e = w1t + (size_t)e * H_DIM * D_DIM + (size_t)n0 * D_DIM;
  int wave = tid >> 6, lane = tid & 63;
  int quad = lane >> 4, l16 = lane & 15;
  int lr = lane >> 3;                        // staging: row within 8-row segment
  int lcs = (((lane & 7) ^ lr)) * 8;         // SWIZZLED source col-slot (elements)
  int wm = (wave >> 2) * 128, wn = (wave & 3) * 64;   // 2M x 4N wave grid
  int l7 = l16 & 7;                          // read-side swizzle key (== row&7)
  f32x4 acc[8][4] = {};

  auto stage = [&](int buf, int k0) {
    #pragma unroll
    for (int i = 0; i < 4; i++) {
      int s = wave * 4 + i;                 // segment: rows [8s, 8s+8), s in [0,32)
      int t = tok[s * 8 + lr];
      gl_lds16(xbf + (size_t)t * D_DIM + k0 + lcs, &xs[buf][s * 512]);
    }
    #pragma unroll
    for (int i = 0; i < 4; i++) {
      int s = wave * 4 + i;
      gl_lds16(w1e + (size_t)(s * 8 + lr) * D_DIM + k0 + lcs, &bs[buf][s * 512]);
    }
  };

  const int nk = D_DIM / BK;  // 8
  stage(0, 0);
  for (int ki = 0; ki < nk; ki++) {
    __syncthreads();                                       // drains buf[ki&1] loads
    if (ki + 1 < nk) stage((ki + 1) & 1, (ki + 1) * BK);   // fly during compute
    const bf16* xsc = xs[ki & 1];
    const bf16* bsc = bs[ki & 1];
    #pragma unroll
    for (int kk = 0; kk < BK; kk += 32) {
      int sw = ((quad + (kk >> 3)) ^ l7) * 8;   // swizzled slot offset (elements)
      bf16x8 bfr[4];
      #pragma unroll
      for (int j = 0; j < 4; j++)
        bfr[j] = *reinterpret_cast<const bf16x8*>(&bsc[(wn + j * 16 + l16) * BK + sw]);
      #pragma unroll
      for (int i = 0; i < 8; i++) {
        bf16x8 af = *reinterpret_cast<const bf16x8*>(&xsc[(wm + i * 16 + l16) * BK + sw]);
        #pragma unroll
        for (int j = 0; j < 4; j++)
          acc[i][j] = __builtin_amdgcn_mfma_f32_16x16x32_bf16(af, bfr[j], acc[i][j], 0, 0, 0);
      }
    }
  }

  bf16* hrow = hbuf + (size_t)(rbase + m0) * H_DIM;
  #pragma unroll
  for (int i = 0; i < 8; i++) {
    int row = wm + i * 16 + quad * 4;
    #pragma unroll
    for (int j = 0; j < 4; j++) {
      int col = n0 + wn + j * 16 + l16;
      float bias = b1[e * H_DIM + col];
      #pragma unroll
      for (int r = 0; r < 4; r++) {
        float v = acc[i][j][r] + bias;
        v = v > 0.f ? v : 0.f;
        hrow[(size_t)(row + r) * H_DIM + col] = (bf16)v;
      }
    }
  }
}

// ---------------- GEMM2: out += 0.5*(h @ W2 + b2), scattered fp32 atomicAdd ----------------
// same 256^2 2-phase structure; NC2 = 2 chunks over D
#define NC2 (D_DIM / BN)   // 2
__global__ __launch_bounds__(512, 2) void gemm2(
    const bf16* __restrict__ hbuf, const bf16* __restrict__ w2t,
    const float* __restrict__ b2, const int* __restrict__ lists,
    const int* __restrict__ cnt, float* __restrict__ out) {
  int lin = blockIdx.x;
  int xcd = lin & 7;
  int rem = lin >> 3;
  int nc  = rem & (NC2 - 1);
  int rb  = (rem >> 1) * 8 + xcd;
  int e   = rb >> 6;
  int m0  = (rb & 63) * BM;
  int ce  = cnt[e];
  if (m0 >= ce) return;
  int n0 = nc * BN;
  int rbase = rowbase_of(cnt, e);

  __shared__ bf16 hs[2][BM * BK];
  __shared__ bf16 bs[2][BN * BK];
  __shared__ int tok[BM];

  int tid = threadIdx.x;
  if (tid < BM) {
    int r = m0 + tid;
    tok[tid] = (r < ce) ? lists[e * NTOK + r] : -1;
  }
  __syncthreads();

  const bf16* hbase = hbuf + (size_t)(rbase + m0) * H_DIM;
  const bf16* w2e = w2t + (size_t)e * H_DIM * D_DIM + (size_t)n0 * H_DIM;
  int wave = tid >> 6, lane = tid & 63;
  int quad = lane >> 4, l16 = lane & 15;
  int lr = lane >> 3;
  int lcs = (((lane & 7) ^ lr)) * 8;         // SWIZZLED source col-slot (elements)
  int wm = (wave >> 2) * 128, wn = (wave & 3) * 64;
  int l7 = l16 & 7;
  f32x4 acc[8][4] = {};

  auto stage = [&](int buf, int k0) {
    #pragma unroll
    for (int i = 0; i < 4; i++) {
      int s = wave * 4 + i;
      gl_lds16(hbase + (size_t)(s * 8 + lr) * H_DIM + k0 + lcs, &hs[buf][s * 512]);
    }
    #pragma unroll
    for (int i = 0; i < 4; i++) {
      int s = wave * 4 + i;
      gl_lds16(w2e + (size_t)(s * 8 + lr) * H_DIM + k0 + lcs, &bs[buf][s * 512]);
    }
  };

  const int nk = H_DIM / BK;  // 32
  stage(0, 0);
  for (int ki = 0; ki < nk; ki++) {
    __syncthreads();
    if (ki + 1 < nk) stage((ki + 1) & 1, (ki + 1) * BK);
    const bf16* hsc = hs[ki & 1];
    const bf16* bsc = bs[ki & 1];
    #pragma unroll
    for (int kk = 0; kk < BK; kk += 32) {
      int sw = ((quad + (kk >> 3)) ^ l7) * 8;
      bf16x8 bfr[4];
      #pragma unroll
      for (int j = 0; j < 4; j++)
        bfr[j] = *reinterpret_cast<const bf16x8*>(&bsc[(wn + j * 16 + l16) * BK + sw]);
      #pragma unroll
      for (int i = 0; i < 8; i++) {
        bf16x8 af = *reinterpret_cast<const bf16x8*>(&hsc[(wm + i * 16 + l16) * BK + sw]);
        #pragma unroll
        for (int j = 0; j < 4; j++)
          acc[i][j] = __builtin_amdgcn_mfma_f32_16x16x32_bf16(af, bfr[j], acc[i][j], 0, 0, 0);
      }
    }
  }

  #pragma unroll
  for (int i = 0; i < 8; i++) {
    int row = wm + i * 16 + quad * 4;
    #pragma unroll
    for (int j = 0; j < 4; j++) {
      int col = n0 + wn + j * 16 + l16;
      float bias = b2[e * D_DIM + col];
      #pragma unroll
      for (int r = 0; r < 4; r++) {
        int t = tok[row + r];
        if (t >= 0) {
          float v = 0.5f * (acc[i][j][r] + bias);
          atomicAdd(&out[(size_t)t * D_DIM + col], v);
        }
      }
    }
  }
}

// ---------------- launch ----------------
extern "C" void kernel_launch(void* const* d_in, const int* in_sizes, int n_in,
                              void* d_out, int out_size, void* d_ws, size_t ws_size,
                              hipStream_t stream) {
  const float* x      = (const float*)d_in[0];
  const int*   assign = (const int*)d_in[1];
  const float* W1     = (const float*)d_in[2];
  const float* b1     = (const float*)d_in[3];
  const float* W2     = (const float*)d_in[4];
  const float* b2     = (const float*)d_in[5];
  float* out = (float*)d_out;
  char* ws = (char*)d_ws;

  int* fill    = (int*)(ws + OFF_FILL);
  int* lists   = (int*)(ws + OFF_LIST);
  bf16* xbf    = (bf16*)(ws + OFF_XBF);
  bf16* w1t    = (bf16*)(ws + OFF_W1T);
  bf16* w2t    = (bf16*)(ws + OFF_W2T);
  bf16* hbuf   = (bf16*)(ws + OFF_HBUF);

  hipMemsetAsync(ws, 0, 128, stream);
  hipMemsetAsync(d_out, 0, (size_t)out_size * sizeof(float), stream);

  fill_kernel<<<NTOK / 256, 256, 0, stream>>>(assign, fill, lists);

  cvt_x<<<(NTOK * D_DIM) / (256 * 8), 256, 0, stream>>>(x, xbf);
  // W1 [E][D][H] -> W1T [E][H][D];  W2 [E][H][D] -> W2T [E][D][H]
  transpose_cvt<<<dim3(H_DIM / 32, D_DIM / 32, E_NUM), dim3(32, 8), 0, stream>>>(W1, w1t, D_DIM, H_DIM);
  transpose_cvt<<<dim3(D_DIM / 32, H_DIM / 32, E_NUM), dim3(32, 8), 0, stream>>>(W2, w2t, H_DIM, D_DIM);

  // 1D swizzled grids: total = (E*NTOK/BM) * NC, encode lin = xcd + 8*(nc + NC*rbHi)
  gemm1<<<(E_NUM * NTOK / BM) * NC1, 512, 0, stream>>>(xbf, w1t, b1, lists, fill, hbuf);
  gemm2<<<(E_NUM * NTOK / BM) * NC2, 512, 0, stream>>>(hbuf, w2t, b2, lists, fill, out);

  (void)in_sizes; (void)n_in; (void)ws_size;
}